// Round 6
// baseline (611.299 us; speedup 1.0000x reference)
//
#include <hip/hip_runtime.h>
#include <cmath>

// Problem dims (fixed by setup_inputs)
#define B_SZ  32
#define LATD  64
#define HU    96
#define G4    384
#define T_LEN 512
#define VOC   10000
#define NROWS (B_SZ * T_LEN)        // 16384
#define NC16  625                   // 10000/16 exactly
#define NSPLIT 5
#define C16S  125                   // c16 tiles per split
#define RBLK  32                    // rows per dense block
#define PPR   (NSPLIT * 2)          // partials per row
#define PACK_BLOCKS ((NC16 * 3 * 64) / 192)         // 625 exactly
#define LSTM_GRID   (B_SZ + PACK_BLOCKS)            // 657

typedef __attribute__((ext_vector_type(8))) short bf16x8;
typedef __attribute__((ext_vector_type(4))) float f32x4;

__device__ __forceinline__ unsigned short f2bf(float x) {
  unsigned u = __float_as_uint(x);
  u += 0x7fffu + ((u >> 16) & 1u);   // RNE
  return (unsigned short)(u >> 16);
}
__device__ __forceinline__ float fsig(float x) {
  return __builtin_amdgcn_rcpf(1.f + __expf(-x));
}
__device__ __forceinline__ float ftanh(float x) {
  return 1.f - 2.f * __builtin_amdgcn_rcpf(1.f + __expf(2.f * x));
}

// ---------------- Kernel 1 (fused): LSTM recurrence + Wd packing ------------
// Blocks [0,32): LSTM, one batch element each, 3 waves (one per SIMD).
//   Replicated-A MFMA: A-fragment = h broadcast to all 16 rows, B = U
//   fragments. Wave w owns tile quads for m = w and m = w+3: gates i,f,cb,o
//   of units u0 = c+16w and u1 = c+16(w+3) land in-lane (c = lane&15) -> no
//   cross-wave gate exchange. Per gate the 3-K-chain is split 2+1 to cut
//   MFMA dependency latency. h double-buffered bf16 in LDS, 1 barrier/step.
// Blocks [32, 657): pack Wd into bf16 MFMA-fragment order (other CUs).
__global__ __launch_bounds__(192) void lstm_fused(
    const float* __restrict__ z, const float* __restrict__ W,
    const float* __restrict__ U, const float* __restrict__ bias,
    const float* __restrict__ Wd, unsigned short* __restrict__ hsb,
    uint4* __restrict__ Bp) {
  const int tid = threadIdx.x;

  if (blockIdx.x >= B_SZ) {
    // ---- pack path: chunk (c16,K16,l): elem j = Wd[K16*32+(l>>4)*8+j][c16*16+(l&15)]
    const int gid = (blockIdx.x - B_SZ) * 192 + tid;
    const int l   = gid & 63;
    const int K16 = (gid >> 6) % 3;
    const int c16 = gid / 192;
    const int col = c16 * 16 + (l & 15);
    const int k0  = K16 * 32 + (l >> 4) * 8;
    unsigned wb[4];
#pragma unroll
    for (int jj = 0; jj < 4; ++jj) {
      float x0 = Wd[(size_t)(k0 + 2 * jj) * VOC + col];
      float x1 = Wd[(size_t)(k0 + 2 * jj + 1) * VOC + col];
      wb[jj] = (unsigned)f2bf(x0) | ((unsigned)f2bf(x1) << 16);
    }
    Bp[gid] = make_uint4(wb[0], wb[1], wb[2], wb[3]);
    return;
  }

  // ---- LSTM path ----
  __shared__ __align__(16) unsigned short hbuf[2][HU];  // bf16 h, double-buffered
  __shared__ float z_lds[LATD];
  const int bb = blockIdx.x;
  const int l  = tid & 63, wv = tid >> 6;   // wave 0..2
  const int c  = l & 15, kg = l >> 4, k0 = kg * 8;

  if (tid < LATD)   z_lds[tid] = z[bb * LATD + tid];
  if (tid < HU / 2) ((unsigned*)hbuf[0])[tid] = 0u;

  // gate g of unit (c + 16*(wv+3u)) lives at col (6g + wv + 3u)*16 + c
  int cols[2][4];
#pragma unroll
  for (int u = 0; u < 2; ++u)
#pragma unroll
    for (int g = 0; g < 4; ++g) cols[u][g] = (6 * g + wv + 3 * u) * 16 + c;

  // U fragments (MFMA B-operand layout): 2 units x 4 gates x 3 kt = 96 VGPRs
  bf16x8 Ufr[2][4][3];
#pragma unroll
  for (int u = 0; u < 2; ++u)
#pragma unroll
    for (int g = 0; g < 4; ++g)
#pragma unroll
      for (int kt = 0; kt < 3; ++kt) {
        const int kb = kt * 32 + k0;
        unsigned wb[4];
#pragma unroll
        for (int jj = 0; jj < 4; ++jj) {
          float x0 = U[(size_t)(kb + 2 * jj) * G4 + cols[u][g]];
          float x1 = U[(size_t)(kb + 2 * jj + 1) * G4 + cols[u][g]];
          wb[jj] = (unsigned)f2bf(x0) | ((unsigned)f2bf(x1) << 16);
        }
        uint4 u4 = make_uint4(wb[0], wb[1], wb[2], wb[3]);
        Ufr[u][g][kt] = __builtin_bit_cast(bf16x8, u4);
      }

  float zp[2][4];
#pragma unroll
  for (int u = 0; u < 2; ++u)
#pragma unroll
    for (int g = 0; g < 4; ++g) zp[u][g] = bias[cols[u][g]];
  __syncthreads();  // z_lds + hbuf[0] ready
  for (int k = 0; k < LATD; ++k) {
    const float zk = z_lds[k];
    const float* wr = W + (size_t)k * G4;
#pragma unroll
    for (int u = 0; u < 2; ++u)
#pragma unroll
      for (int g = 0; g < 4; ++g) zp[u][g] = fmaf(zk, wr[cols[u][g]], zp[u][g]);
  }

  float cst[2] = {0.f, 0.f};
  unsigned short* hrow = hsb + (size_t)bb * T_LEN * HU;
  int p = 0;
  const f32x4 zero4 = {0.f, 0.f, 0.f, 0.f};
  const int u0 = c + 16 * wv, u1 = u0 + 48;

  for (int s = 0; s < T_LEN; ++s) {
    bf16x8 afr[3];
#pragma unroll
    for (int kt = 0; kt < 3; ++kt)
      afr[kt] = *(const bf16x8*)(&hbuf[p][kt * 32 + k0]);

    float gate[2][4];
#pragma unroll
    for (int u = 0; u < 2; ++u)
#pragma unroll
      for (int g = 0; g < 4; ++g) {
        f32x4 da = __builtin_amdgcn_mfma_f32_16x16x32_bf16(afr[0], Ufr[u][g][0], zero4, 0, 0, 0);
        da = __builtin_amdgcn_mfma_f32_16x16x32_bf16(afr[2], Ufr[u][g][2], da, 0, 0, 0);
        f32x4 db = __builtin_amdgcn_mfma_f32_16x16x32_bf16(afr[1], Ufr[u][g][1], zero4, 0, 0, 0);
        gate[u][g] = (da[0] + db[0]) + zp[u][g];
      }

    unsigned short hb[2];
#pragma unroll
    for (int u = 0; u < 2; ++u) {
      const float i_ = fsig(gate[u][0]);
      const float f_ = fsig(gate[u][1]);
      const float cb = ftanh(gate[u][2]);
      const float o_ = fsig(gate[u][3]);
      cst[u] = f_ * cst[u] + i_ * cb;
      hb[u] = f2bf(o_ * ftanh(cst[u]));
    }
    // one op per lane: kg0/kg3 -> LDS (critical), kg1/kg2 -> global (off path)
    if (kg == 0)      hbuf[p ^ 1][u0] = hb[0];
    else if (kg == 3) hbuf[p ^ 1][u1] = hb[1];
    else if (kg == 1) hrow[(size_t)s * HU + u0] = hb[0];
    else              hrow[(size_t)s * HU + u1] = hb[1];
    __syncthreads();
    p ^= 1;
  }
}

// ---------------- Kernels 2/3: dense GEMM passes (operand-swapped) ----------
// Grid: 512 row-blocks x NSPLIT v-splits (bid: s=bid/512, rb=bid%512).
// 4 waves: rt = wv&1 (16-row tile), cg = wv>>1 (odd/even c16 within split).
// Operand swap: acc = mfma(Wd_frag, hs_frag) -> lane (l15,l4) holds, for
// q=0..3, out[row = R0+rt*16+l15][col = c16*16 + l4*4 + q]: 4 consecutive
// cols of ONE row => float4 stores, float4 bd loads, 2-shfl row reduction.
// PASS 0: partial sum(exp(logit)) -> part[row][s*2+cg].
// PASS 1: sums part inline -> invS; recomputes logits -> nontemporal out.
template <int PASS>
__global__ __launch_bounds__(256) void dense_pass(
    const unsigned short* __restrict__ hsb, const bf16x8* __restrict__ Bp,
    const float* __restrict__ bd, const float* __restrict__ part,
    float* __restrict__ outp) {
  __shared__ __align__(16) unsigned short Al[RBLK * HU];  // 6 KB
  const int tid = threadIdx.x;
  const int l = tid & 63, wv = tid >> 6;
  const int rt = wv & 1, cg = wv >> 1;
  const int l15 = l & 15, l4 = l >> 4;
  const int s = blockIdx.x / 512, rb = blockIdx.x % 512;
  const int R0 = rb * RBLK;

  {
    const uint4* src = (const uint4*)(hsb + (size_t)R0 * HU);
    uint4* dst = (uint4*)Al;
    for (int i = tid; i < RBLK * HU / 8; i += 256) dst[i] = src[i];
  }
  __syncthreads();

  bf16x8 afr[3];
#pragma unroll
  for (int kt = 0; kt < 3; ++kt)
    afr[kt] = *(const bf16x8*)(Al + (rt * 16 + l15) * HU + kt * 32 + l4 * 8);

  const int row = R0 + rt * 16 + l15;
  float iv = 0.f;
  if (PASS == 1) {
    float sum = 0.f;
#pragma unroll
    for (int i = 0; i < PPR; ++i) sum += part[(size_t)row * PPR + i];
    iv = 1.f / sum;
  }

  float srun = 0.f;
  for (int i = cg; i < C16S; i += 2) {
    const int c16 = s * C16S + i;
    const bf16x8* bp = Bp + (size_t)c16 * 192 + l;
    const bf16x8 b0 = bp[0], b1 = bp[64], b2 = bp[128];
    f32x4 acc = {0.f, 0.f, 0.f, 0.f};
    acc = __builtin_amdgcn_mfma_f32_16x16x32_bf16(b0, afr[0], acc, 0, 0, 0);
    acc = __builtin_amdgcn_mfma_f32_16x16x32_bf16(b1, afr[1], acc, 0, 0, 0);
    acc = __builtin_amdgcn_mfma_f32_16x16x32_bf16(b2, afr[2], acc, 0, 0, 0);
    const int colb = c16 * 16 + l4 * 4;
    const f32x4 bd4 = *(const f32x4*)(bd + colb);
    if (PASS == 0) {
#pragma unroll
      for (int q = 0; q < 4; ++q) srun += __expf(acc[q] + bd4[q]);
    } else {
      f32x4 o;
#pragma unroll
      for (int q = 0; q < 4; ++q) o[q] = __expf(acc[q] + bd4[q]) * iv;
      __builtin_nontemporal_store(o, (f32x4*)(outp + (size_t)row * VOC + colb));
    }
  }

  if (PASS == 0) {
    // combine the 4 col-quad lanes (l4 = 0..3) sharing this row
    srun += __shfl_xor(srun, 16);
    srun += __shfl_xor(srun, 32);
    if (l4 == 0)
      ((float*)outp)[(size_t)row * PPR + s * 2 + cg] = srun;  // outp = part buf
  }
}

extern "C" void kernel_launch(void* const* d_in, const int* in_sizes, int n_in,
                              void* d_out, int out_size, void* d_ws, size_t ws_size,
                              hipStream_t stream) {
  const float* z  = (const float*)d_in[0];
  const float* W  = (const float*)d_in[1];
  const float* U  = (const float*)d_in[2];
  const float* b  = (const float*)d_in[3];
  const float* Wd = (const float*)d_in[4];
  const float* bd = (const float*)d_in[5];
  float* out = (float*)d_out;

  char* ws = (char*)d_ws;
  unsigned short* hsb = (unsigned short*)ws;                 // 3,145,728 B
  uint4* Bp   = (uint4*)(ws + 3145728);                      // 1,920,000 B
  float* part = (float*)(ws + 3145728 + 1920000);            //   655,360 B

  lstm_fused<<<LSTM_GRID, 192, 0, stream>>>(z, W, U, b, Wd, hsb, Bp);
  dense_pass<0><<<512 * NSPLIT, 256, 0, stream>>>(hsb, (const bf16x8*)Bp, bd,
                                                  nullptr, part);
  dense_pass<1><<<512 * NSPLIT, 256, 0, stream>>>(hsb, (const bf16x8*)Bp, bd,
                                                  part, out);
}

// Round 7
// 516.134 us; speedup vs baseline: 1.1844x; 1.1844x over previous
//
#include <hip/hip_runtime.h>
#include <cmath>

// Problem dims (fixed by setup_inputs)
#define B_SZ  32
#define LATD  64
#define HU    96
#define G4    384
#define T_LEN 512
#define VOC   10000
#define NROWS (B_SZ * T_LEN)        // 16384
#define NC16  625                   // 10000/16 exactly
#define NSPLIT 5
#define C16S  125                   // c16 tiles per split
#define RBLK  32                    // rows per dense block
#define PPR   (NSPLIT * 2)          // partials per row
#define HIST  256                   // LDS h-history ring depth (dump twice)
#define PACK_BLOCKS ((NC16 * 3 * 64 + 383) / 384)   // 313
#define LSTM_GRID   (B_SZ + PACK_BLOCKS)            // 345

typedef __attribute__((ext_vector_type(8))) short bf16x8;
typedef __attribute__((ext_vector_type(4))) float f32x4;

__device__ __forceinline__ unsigned short f2bf(float x) {
  unsigned u = __float_as_uint(x);
  u += 0x7fffu + ((u >> 16) & 1u);   // RNE
  return (unsigned short)(u >> 16);
}
__device__ __forceinline__ float fsig(float x) {
  return __builtin_amdgcn_rcpf(1.f + __expf(-x));
}
__device__ __forceinline__ float ftanh(float x) {
  return 1.f - 2.f * __builtin_amdgcn_rcpf(1.f + __expf(2.f * x));
}

// ---------------- Kernel 1 (fused): LSTM recurrence + Wd packing ------------
// Blocks [0,32): LSTM, one batch element each, 6 waves.
//   Replicated-A MFMA: A-fragment = h broadcast to all 16 rows, B = U
//   fragments. Wave w owns tiles {w, 6+w, 12+w, 18+w} = gates i,f,cb,o of
//   unit u0 = c + 16w (c = lane&15) -> complete gate quad in-lane.
//   h history kept in a 256-row LDS ring (read row s-1, write row s); NO
//   global ops in the step loop (the pre-barrier vmcnt(0) drain was the
//   hidden per-step cost). Ring dumped to global twice (s=255, 511) with
//   coalesced uint4 stores.
// Blocks [32, 345): pack Wd into bf16 MFMA-fragment order (other CUs).
__global__ __launch_bounds__(384) void lstm_fused(
    const float* __restrict__ z, const float* __restrict__ W,
    const float* __restrict__ U, const float* __restrict__ bias,
    const float* __restrict__ Wd, unsigned short* __restrict__ hsb,
    uint4* __restrict__ Bp) {
  const int tid = threadIdx.x;

  if (blockIdx.x >= B_SZ) {
    // ---- pack path: chunk (c16,K16,l): elem j = Wd[K16*32+(l>>4)*8+j][c16*16+(l&15)]
    const int gid = (blockIdx.x - B_SZ) * 384 + tid;
    if (gid < NC16 * 3 * 64) {
      const int l   = gid & 63;
      const int K16 = (gid >> 6) % 3;
      const int c16 = gid / 192;
      const int col = c16 * 16 + (l & 15);
      const int k0  = K16 * 32 + (l >> 4) * 8;
      unsigned wb[4];
#pragma unroll
      for (int jj = 0; jj < 4; ++jj) {
        float x0 = Wd[(size_t)(k0 + 2 * jj) * VOC + col];
        float x1 = Wd[(size_t)(k0 + 2 * jj + 1) * VOC + col];
        wb[jj] = (unsigned)f2bf(x0) | ((unsigned)f2bf(x1) << 16);
      }
      Bp[gid] = make_uint4(wb[0], wb[1], wb[2], wb[3]);
    }
    return;
  }

  // ---- LSTM path ----
  __shared__ __align__(16) unsigned short hsring[HIST][HU];  // 48 KB bf16 ring
  __shared__ float z_lds[LATD];
  const int bb = blockIdx.x;
  const int l  = tid & 63, wv = tid >> 6;   // wave 0..5
  const int c  = l & 15, kg = l >> 4, k0 = kg * 8;

  if (tid < LATD) z_lds[tid] = z[bb * LATD + tid];
  if (tid < 12)   ((uint4*)(hsring[HIST - 1]))[tid] = make_uint4(0u, 0u, 0u, 0u);

  // this lane's 4 gate columns: gate g of unit (c + 16*wv) = col (6g+wv)*16+c
  int cols[4];
#pragma unroll
  for (int g = 0; g < 4; ++g) cols[g] = (6 * g + wv) * 16 + c;

  // U fragments (MFMA B-operand layout): 48 VGPRs
  bf16x8 Ufr[4][3];
#pragma unroll
  for (int g = 0; g < 4; ++g) {
#pragma unroll
    for (int kt = 0; kt < 3; ++kt) {
      const int kb = kt * 32 + k0;
      unsigned wb[4];
#pragma unroll
      for (int jj = 0; jj < 4; ++jj) {
        float x0 = U[(size_t)(kb + 2 * jj) * G4 + cols[g]];
        float x1 = U[(size_t)(kb + 2 * jj + 1) * G4 + cols[g]];
        wb[jj] = (unsigned)f2bf(x0) | ((unsigned)f2bf(x1) << 16);
      }
      uint4 u4 = make_uint4(wb[0], wb[1], wb[2], wb[3]);
      Ufr[g][kt] = __builtin_bit_cast(bf16x8, u4);
    }
  }

  float zp[4];
#pragma unroll
  for (int g = 0; g < 4; ++g) zp[g] = bias[cols[g]];
  __syncthreads();  // z_lds + ring init visible
  for (int k = 0; k < LATD; ++k) {
    const float zk = z_lds[k];
    const float* wr = W + (size_t)k * G4;
#pragma unroll
    for (int g = 0; g < 4; ++g) zp[g] = fmaf(zk, wr[cols[g]], zp[g]);
  }

  float cst = 0.f;
  unsigned short* hrow = hsb + (size_t)bb * T_LEN * HU;
  const f32x4 zero4 = {0.f, 0.f, 0.f, 0.f};
  const int u0 = c + 16 * wv;

  for (int s = 0; s < T_LEN; ++s) {
    const int rs = (s + HIST - 1) & (HIST - 1);
    bf16x8 afr[3];
#pragma unroll
    for (int kt = 0; kt < 3; ++kt)
      afr[kt] = *(const bf16x8*)(&hsring[rs][kt * 32 + k0]);

    float g4[4];
#pragma unroll
    for (int g = 0; g < 4; ++g) {
      f32x4 da = __builtin_amdgcn_mfma_f32_16x16x32_bf16(afr[0], Ufr[g][0], zero4, 0, 0, 0);
      da = __builtin_amdgcn_mfma_f32_16x16x32_bf16(afr[2], Ufr[g][2], da, 0, 0, 0);
      f32x4 db = __builtin_amdgcn_mfma_f32_16x16x32_bf16(afr[1], Ufr[g][1], zero4, 0, 0, 0);
      g4[g] = (da[0] + db[0]) + zp[g];
    }

    const float i_ = fsig(g4[0]);
    const float f_ = fsig(g4[1]);
    const float cb = ftanh(g4[2]);
    const float o_ = fsig(g4[3]);
    cst = f_ * cst + i_ * cb;
    const float h = o_ * ftanh(cst);
    if (kg == 0) hsring[s & (HIST - 1)][u0] = f2bf(h);
    __syncthreads();

    if ((s & (HIST - 1)) == (HIST - 1)) {
      // bulk dump rows s-255..s (slots 0..255): 48 KB coalesced
      const uint4* srcp = (const uint4*)hsring;
      uint4* dstp = (uint4*)(hrow + (size_t)(s - (HIST - 1)) * HU);
      for (int i = tid; i < HIST * HU / 8; i += 384) dstp[i] = srcp[i];
      __syncthreads();  // ring reusable only after all dump reads done
    }
  }
}

// ---------------- Kernels 2/3: dense GEMM passes (operand-swapped) ----------
// Grid: 512 row-blocks x NSPLIT v-splits (bid: s=bid/512, rb=bid%512).
// 4 waves: rt = wv&1 (16-row tile), cg = wv>>1 (odd/even c16 within split).
// Operand swap: acc = mfma(Wd_frag, hs_frag) -> lane (l15,l4) holds, for
// q=0..3, out[row = R0+rt*16+l15][col = c16*16 + l4*4 + q]: 4 consecutive
// cols of ONE row => float4 stores, float4 bd loads, 2-shfl row reduction.
// PASS 0: partial sum(exp(logit)) -> part[row][s*2+cg].
// PASS 1: sums part inline -> invS; recomputes logits -> nontemporal out.
template <int PASS>
__global__ __launch_bounds__(256) void dense_pass(
    const unsigned short* __restrict__ hsb, const bf16x8* __restrict__ Bp,
    const float* __restrict__ bd, const float* __restrict__ part,
    float* __restrict__ outp) {
  __shared__ __align__(16) unsigned short Al[RBLK * HU];  // 6 KB
  const int tid = threadIdx.x;
  const int l = tid & 63, wv = tid >> 6;
  const int rt = wv & 1, cg = wv >> 1;
  const int l15 = l & 15, l4 = l >> 4;
  const int s = blockIdx.x / 512, rb = blockIdx.x % 512;
  const int R0 = rb * RBLK;

  {
    const uint4* src = (const uint4*)(hsb + (size_t)R0 * HU);
    uint4* dst = (uint4*)Al;
    for (int i = tid; i < RBLK * HU / 8; i += 256) dst[i] = src[i];
  }
  __syncthreads();

  bf16x8 afr[3];
#pragma unroll
  for (int kt = 0; kt < 3; ++kt)
    afr[kt] = *(const bf16x8*)(Al + (rt * 16 + l15) * HU + kt * 32 + l4 * 8);

  const int row = R0 + rt * 16 + l15;
  float iv = 0.f;
  if (PASS == 1) {
    float sum = 0.f;
#pragma unroll
    for (int i = 0; i < PPR; ++i) sum += part[(size_t)row * PPR + i];
    iv = 1.f / sum;
  }

  float srun = 0.f;
  for (int i = cg; i < C16S; i += 2) {
    const int c16 = s * C16S + i;
    const bf16x8* bp = Bp + (size_t)c16 * 192 + l;
    const bf16x8 b0 = bp[0], b1 = bp[64], b2 = bp[128];
    f32x4 acc = {0.f, 0.f, 0.f, 0.f};
    acc = __builtin_amdgcn_mfma_f32_16x16x32_bf16(b0, afr[0], acc, 0, 0, 0);
    acc = __builtin_amdgcn_mfma_f32_16x16x32_bf16(b1, afr[1], acc, 0, 0, 0);
    acc = __builtin_amdgcn_mfma_f32_16x16x32_bf16(b2, afr[2], acc, 0, 0, 0);
    const int colb = c16 * 16 + l4 * 4;
    const f32x4 bd4 = *(const f32x4*)(bd + colb);
    if (PASS == 0) {
#pragma unroll
      for (int q = 0; q < 4; ++q) srun += __expf(acc[q] + bd4[q]);
    } else {
      f32x4 o;
#pragma unroll
      for (int q = 0; q < 4; ++q) o[q] = __expf(acc[q] + bd4[q]) * iv;
      __builtin_nontemporal_store(o, (f32x4*)(outp + (size_t)row * VOC + colb));
    }
  }

  if (PASS == 0) {
    // combine the 4 col-quad lanes (l4 = 0..3) sharing this row
    srun += __shfl_xor(srun, 16);
    srun += __shfl_xor(srun, 32);
    if (l4 == 0)
      ((float*)outp)[(size_t)row * PPR + s * 2 + cg] = srun;  // outp = part buf
  }
}

extern "C" void kernel_launch(void* const* d_in, const int* in_sizes, int n_in,
                              void* d_out, int out_size, void* d_ws, size_t ws_size,
                              hipStream_t stream) {
  const float* z  = (const float*)d_in[0];
  const float* W  = (const float*)d_in[1];
  const float* U  = (const float*)d_in[2];
  const float* b  = (const float*)d_in[3];
  const float* Wd = (const float*)d_in[4];
  const float* bd = (const float*)d_in[5];
  float* out = (float*)d_out;

  char* ws = (char*)d_ws;
  unsigned short* hsb = (unsigned short*)ws;                 // 3,145,728 B
  uint4* Bp   = (uint4*)(ws + 3145728);                      // 1,920,000 B
  float* part = (float*)(ws + 3145728 + 1920000);            //   655,360 B

  lstm_fused<<<LSTM_GRID, 384, 0, stream>>>(z, W, U, b, Wd, hsb, Bp);
  dense_pass<0><<<512 * NSPLIT, 256, 0, stream>>>(hsb, (const bf16x8*)Bp, bd,
                                                  nullptr, part);
  dense_pass<1><<<512 * NSPLIT, 256, 0, stream>>>(hsb, (const bf16x8*)Bp, bd,
                                                  part, out);
}